// Round 8
// baseline (297.035 us; speedup 1.0000x reference)
//
#include <hip/hip_runtime.h>

typedef short short8 __attribute__((ext_vector_type(8)));
typedef float f32x4 __attribute__((ext_vector_type(4)));
typedef unsigned short ushort4v __attribute__((ext_vector_type(4)));

#define MFMA(a, b, c) __builtin_amdgcn_mfma_f32_16x16x32_bf16((a), (b), (c), 0, 0, 0)

__device__ __forceinline__ short f2bf(float f) {
  union { float f; unsigned u; } v; v.f = f;
  unsigned r = v.u + 0x7fffu + ((v.u >> 16) & 1u);  // RNE
  return (short)(r >> 16);
}

// async global->LDS, 16B per lane, lane i lands at ldsbase + i*16 (linear!)
__device__ __forceinline__ void glds16(const short* g, short* l) {
  __builtin_amdgcn_global_load_lds((const __attribute__((address_space(1))) void*)g,
                                   (__attribute__((address_space(3))) void*)l, 16, 0, 0);
}

// ---------------- kernel 1: convert weights/biases to bf16 / packed ----------
__global__ __launch_bounds__(256) void convert_w(
    const float* __restrict__ Wq, const float* __restrict__ Wk,
    const float* __restrict__ Wv, const float* __restrict__ Wo,
    const float* __restrict__ bq, const float* __restrict__ bk,
    const float* __restrict__ bv,
    short* __restrict__ Wb3, short* __restrict__ Wob, float* __restrict__ b3) {
  int idx = blockIdx.x * 256 + threadIdx.x;
  const int NW3 = 768 * 512, NWO = 512 * 256;
  if (idx < NW3) {
    int o = idx >> 9, cix = idx & 511;
    const float* W = (o < 256) ? Wq : (o < 512) ? Wk : Wv;
    Wb3[idx] = f2bf(W[(o & 255) * 512 + cix]);
  } else if (idx < NW3 + NWO) {
    int i2 = idx - NW3;
    Wob[i2] = f2bf(Wo[i2]);
  } else if (idx < NW3 + NWO + 768) {
    int i3 = idx - (NW3 + NWO);
    b3[i3] = (i3 < 256) ? bq[i3] : (i3 < 512) ? bk[i3 - 256] : bv[i3 - 512];
  }
}

// ---------------- kernel 2: x1 (B,512,L) fp32 -> xT (B,L,512) bf16 ----------
// 64x64 tile, 256 threads. Loads: 4x float4/lane (16B, 256B-contiguous runs).
// LDS fp32 [64][65] (pad -> transposed read ~2-way conflict = free, m136).
// Stores: 2x short8/lane (16B, 128B-contiguous runs). G13: width is the fix.
__global__ __launch_bounds__(256) void transpose_x(const float* __restrict__ x,
                                                   short* __restrict__ xT) {
  __shared__ float t[64][65];
  int b = blockIdx.z, c0 = blockIdx.y * 64, l0 = blockIdx.x * 64;
  int tid = threadIdx.x;
  {
    int cl = tid >> 2, ls = (tid & 3) * 16;  // c-row 0..63, l-seg 0..3
    const float* xb = x + ((size_t)b * 512 + c0 + cl) * 8192 + l0 + ls;
#pragma unroll
    for (int i = 0; i < 4; i++) {
      f32x4 v = *(const f32x4*)(xb + i * 4);
      *(f32x4*)&t[cl][ls + i * 4] = v;
    }
  }
  __syncthreads();
  {
    int ll = tid >> 2, cs = (tid & 3) * 16;  // l-row 0..63, c-seg 0..3
    short8 pk[2];
#pragma unroll
    for (int h = 0; h < 2; h++)
#pragma unroll
      for (int j = 0; j < 8; j++) pk[h][j] = f2bf(t[cs + h * 8 + j][ll]);
    short* xo = xT + ((size_t)b * 8192 + l0 + ll) * 512 + c0 + cs;
    *(short8*)(xo) = pk[0];
    *(short8*)(xo + 8) = pk[1];
  }
}

// ---------------- kernel 3: QKV projection GEMM (m97 structure) ----------
// C[m][n] = sum_k Wb3[m][k] * xT[n][k]; 128x128 tile, 4 waves of 64x64,
// BK=32, global_load_lds(16B) staging into linear LDS, 2-barrier loop.
// 1-D grid (1536) + T1 XCD swizzle: the 6 mtile blocks sharing a (n0,b)
// B-panel (128 KB of xT) land at ids with equal (id % 8) -> same XCD ->
// panel fetched into that XCD's L2 once, L2-hit 5x (bijective: 192 = 6*32).
// q,k stored transposed (l, c) bf16; v stored natural (c, l) bf16.
__global__ __launch_bounds__(256, 2) void gemm_qkv(
    const short* __restrict__ Wb3, const float* __restrict__ b3,
    const short* __restrict__ xT, short* __restrict__ q_t,
    short* __restrict__ k_t, short* __restrict__ v_tt) {
  __shared__ __align__(16) short lds[8192];  // A[128][32] | B[128][32]
  int t = threadIdx.x, w = t >> 6, l = t & 63;
  int r = l & 15, g = l >> 4;
  int wr = w >> 1, wc = w & 1;
  // --- XCD-locality swizzle decode (bijective over 1536) ---
  int id = blockIdx.x;
  int xcd = id & 7, j = id >> 3;      // j in 0..191
  int grp = j / 6, mtile = j - 6 * grp;  // grp 0..31, mtile 0..5
  int g_total = xcd * 32 + grp;       // 0..255
  int n0 = (g_total >> 2) * 128, b = g_total & 3;
  int m00 = mtile * 128;
  const short* Ab = Wb3 + (size_t)m00 * 512;
  const short* Bb = xT + (size_t)b * 8192 * 512 + (size_t)n0 * 512;
  int c0 = w * 64 + l, c1 = 256 + w * 64 + l;  // chunk ids (8 bf16 each)
  int a0r = c0 >> 2, a0c = (c0 & 3) * 8, a1r = c1 >> 2, a1c = (c1 & 3) * 8;

  f32x4 acc[4][4];
#pragma unroll
  for (int i = 0; i < 4; i++)
#pragma unroll
    for (int jj = 0; jj < 4; jj++) acc[i][jj] = {0.f, 0.f, 0.f, 0.f};

  for (int kk = 0; kk < 16; kk++) {
    const short* ga = Ab + kk * 32;
    const short* gb = Bb + kk * 32;
    glds16(ga + (size_t)a0r * 512 + a0c, lds + (w * 64) * 8);
    glds16(ga + (size_t)a1r * 512 + a1c, lds + (256 + w * 64) * 8);
    glds16(gb + (size_t)a0r * 512 + a0c, lds + 4096 + (w * 64) * 8);
    glds16(gb + (size_t)a1r * 512 + a1c, lds + 4096 + (256 + w * 64) * 8);
    __syncthreads();  // compiler drains vmcnt before s_barrier
    short8 af[4], bfv[4];
#pragma unroll
    for (int mt = 0; mt < 4; mt++)
      af[mt] = *(const short8*)(lds + (wr * 64 + mt * 16 + r) * 32 + g * 8);
#pragma unroll
    for (int nt = 0; nt < 4; nt++)
      bfv[nt] = *(const short8*)(lds + 4096 + (wc * 64 + nt * 16 + r) * 32 + g * 8);
#pragma unroll
    for (int mt = 0; mt < 4; mt++)
#pragma unroll
      for (int nt = 0; nt < 4; nt++) acc[mt][nt] = MFMA(af[mt], bfv[nt], acc[mt][nt]);
    __syncthreads();
  }

  if (mtile < 4) {  // q (mtile 0,1) / k (mtile 2,3), transposed (l, c) layout
    short* dst = ((mtile < 2) ? q_t : k_t) + (size_t)b * 8192 * 256;
    int cb = (mtile & 1) * 128 + wr * 64;
#pragma unroll
    for (int nt = 0; nt < 4; nt++) {
      int n = n0 + wc * 64 + nt * 16 + r;
#pragma unroll
      for (int mt = 0; mt < 4; mt++) {
        ushort4v pk;
#pragma unroll
        for (int jj = 0; jj < 4; jj++)
          pk[jj] = (unsigned short)f2bf(acc[mt][nt][jj] + b3[m00 + wr * 64 + mt * 16 + 4 * g + jj]);
        *(ushort4v*)(dst + (size_t)n * 256 + cb + mt * 16 + 4 * g) = pk;
      }
    }
  } else {  // v, natural (c, l) layout
    short* dst = v_tt + (size_t)b * 256 * 8192;
    int cb = (mtile - 4) * 128 + wr * 64;
#pragma unroll
    for (int mt = 0; mt < 4; mt++)
#pragma unroll
      for (int jj = 0; jj < 4; jj++) {
        int c = cb + mt * 16 + 4 * g + jj;
        float bias = b3[512 + c];
#pragma unroll
        for (int nt = 0; nt < 4; nt++)
          dst[(size_t)c * 8192 + n0 + wc * 64 + nt * 16 + r] = f2bf(acc[mt][nt][jj] + bias);
      }
  }
}

// ---------------- kernel 4: sliding-window flash attention ----------------
// 1-D grid (512 WGs), 4 waves/WG, each wave owns 16 q rows. Grid swizzle
// co-locates the 8 WGs sharing a (blk, b) K/V window at ids with equal
// (id % 8) -> same XCD under round-robin dispatch -> window fetched into
// that XCD's L2 once, reused 8x (bijective remap; perf-only heuristic).
// K chunk (64x256) and V chunk (256x64) staged in LDS once per WG, shared by
// all 4 waves. T14 split: chunk ch+1's global loads issue to REGISTERS right
// after the staging barrier (hidden under ch's QK+softmax+PV); ds_writes land
// at the top of the next iteration. P-tile has its own LDS region (wave-
// private, no barrier needed). 2 barriers/chunk. XOR-swizzle (slot ^= row&7)
// on both write and read sides. OOB rows staged as ZEROS -> padded energy
// = 0 + log(1e-6), matching the reference's zero-pad semantics.
// T13 defer-max (THR=8): skip O/lsum rescale while max growth <= 8 (P then
// bounded by e^8; numerator/denominator stay consistently scaled).
// T5 s_setprio(1) around both MFMA clusters.
__global__ __launch_bounds__(256, 2) void attn(
    const short* __restrict__ q_t, const short* __restrict__ k_t,
    const short* __restrict__ v_tt, const float* __restrict__ mask,
    short* __restrict__ attout) {
  // bytes: [0,32768) K 64x256 | [32768,65536) V 256x64 | [65536,74752) P 4x16x72
  __shared__ __align__(16) short kv[37376];
  int t = threadIdx.x;
  int lane = t & 63, w = t >> 6;
  int r = lane & 15, g = lane >> 4;
  // --- XCD-locality swizzle decode (bijective) ---
  int id = blockIdx.x;          // 0..511
  int xcd = id & 7, m8 = id >> 3;
  int qtile = m8 & 7;           // window-sharing index
  int grp = ((m8 >> 3) << 3) + xcd;  // 0..63
  int blk = grp & 15, b = grp >> 4;
  const short* qtb = q_t + (size_t)b * 8192 * 256;
  const short* ktb = k_t + (size_t)b * 8192 * 256;
  const short* vtb = v_tt + (size_t)b * 256 * 8192;
  const float* mrow = mask + (size_t)b * 8192;
  int q0 = blk * 512 + qtile * 64 + w * 16;
  short* plds_w = kv + 32768 + w * 1152;  // per-wave 16x72 P tile

  short8 qf[8];
#pragma unroll
  for (int cc = 0; cc < 8; cc++)
    qf[cc] = *(const short8*)(qtb + (size_t)(q0 + r) * 256 + cc * 32 + g * 8);

  f32x4 zero = {0.f, 0.f, 0.f, 0.f};
  short8 zero8 = {0, 0, 0, 0, 0, 0, 0, 0};
  f32x4 o[16];
#pragma unroll
  for (int i = 0; i < 16; i++) o[i] = zero;
  float m_run[4] = {-1e30f, -1e30f, -1e30f, -1e30f};
  float lsum[4] = {0.f, 0.f, 0.f, 0.f};
  int wbase = blk * 512 - 256;

  // staged registers for the next chunk (T14 issue-early / write-late)
  short8 kreg[8], vreg[8];
  auto ld_chunk = [&](int kbase) {
#pragma unroll
    for (int i = 0; i < 8; i++) {
      int s = t + i * 256;
      int row = s >> 5, sl = s & 31;
      int kg = kbase + row;
      kreg[i] = zero8;
      if (kg >= 0 && kg < 8192) kreg[i] = *(const short8*)(ktb + (size_t)kg * 256 + sl * 8);
    }
#pragma unroll
    for (int i = 0; i < 8; i++) {
      int s = t + i * 256;
      int chn = s >> 3, sl = s & 7;
      int kg = kbase + sl * 8;
      vreg[i] = zero8;
      if (kg >= 0 && kg <= 8192 - 8) vreg[i] = *(const short8*)(vtb + (size_t)chn * 8192 + kg);
    }
  };
  auto st_chunk = [&]() {
#pragma unroll
    for (int i = 0; i < 8; i++) {
      int s = t + i * 256;
      int row = s >> 5, sl = s & 31;
      *(short8*)(kv + row * 256 + ((sl ^ (row & 7)) * 8)) = kreg[i];
    }
#pragma unroll
    for (int i = 0; i < 8; i++) {
      int s = t + i * 256;
      int chn = s >> 3, sl = s & 7;
      *(short8*)(kv + 16384 + chn * 64 + ((sl ^ (chn & 7)) * 8)) = vreg[i];
    }
  };

  ld_chunk(wbase);  // prologue: chunk 0 -> registers

  for (int ch = 0; ch < 16; ch++) {
    int kbase = wbase + ch * 64;
    st_chunk();      // regs -> LDS (loop-end barrier guaranteed readers done)
    __syncthreads(); // staging visible to all waves
    if (ch < 15) ld_chunk(kbase + 64);  // issue next chunk's loads NOW

    // ---- QK^T from LDS ----
    f32x4 e[4];
    float lm[4], mvv[4];
    __builtin_amdgcn_s_setprio(1);
#pragma unroll
    for (int kt = 0; kt < 4; kt++) {
      e[kt] = zero;
      int kg = kbase + kt * 16 + r;
      bool val = (kg >= 0) && (kg < 8192);
      float mv = val ? mrow[kg] : 0.f;
      mvv[kt] = mv;
      lm[kt] = __logf(mv + 1e-6f);
      const short* kr = kv + (kt * 16 + r) * 256;
#pragma unroll
      for (int cc = 0; cc < 8; cc++) {
        short8 kf = *(const short8*)(kr + (((cc * 4 + g) ^ (r & 7)) * 8));
        e[kt] = MFMA(qf[cc], kf, e[kt]);
      }
    }
    __builtin_amdgcn_s_setprio(0);
    // ---- online softmax (registers only) ----
#pragma unroll
    for (int kt = 0; kt < 4; kt++)
#pragma unroll
      for (int j = 0; j < 4; j++) e[kt][j] = e[kt][j] * 0.0625f + lm[kt];
    float mx[4];
#pragma unroll
    for (int j = 0; j < 4; j++)
      mx[j] = fmaxf(fmaxf(e[0][j], e[1][j]), fmaxf(e[2][j], e[3][j]));
#pragma unroll
    for (int d = 1; d < 16; d <<= 1)
#pragma unroll
      for (int j = 0; j < 4; j++) mx[j] = fmaxf(mx[j], __shfl_xor(mx[j], d));
    // T13 defer-max: only rescale when some row grew by > THR (wave-uniform)
    float need = 0.f;
#pragma unroll
    for (int j = 0; j < 4; j++) need = fmaxf(need, mx[j] - m_run[j]);
    if (!__all(need <= 8.f)) {
      float scl[4];
#pragma unroll
      for (int j = 0; j < 4; j++) {
        float mn = fmaxf(m_run[j], mx[j]);
        scl[j] = __expf(m_run[j] - mn);
        m_run[j] = mn;
        lsum[j] *= scl[j];
      }
#pragma unroll
      for (int ct = 0; ct < 16; ct++)
#pragma unroll
        for (int j = 0; j < 4; j++) o[ct][j] *= scl[j];
    }
#pragma unroll
    for (int kt = 0; kt < 4; kt++)
#pragma unroll
      for (int j = 0; j < 4; j++) {
        float p = __expf(e[kt][j] - m_run[j]);  // bounded by e^8 between rescales
        lsum[j] += p;            // denominator includes padded terms (matches ref)
        e[kt][j] = p * mvv[kt];  // numerator masked
      }

    // ---- P -> LDS (C-frag -> A-frag relayout), wave-private, no barrier ----
#pragma unroll
    for (int kt = 0; kt < 4; kt++)
#pragma unroll
      for (int j = 0; j < 4; j++)
        plds_w[(4 * g + j) * 72 + kt * 16 + r] = f2bf(e[kt][j]);

    // ---- PV from LDS ----
    __builtin_amdgcn_s_setprio(1);
#pragma unroll
    for (int ks = 0; ks < 2; ks++) {
      short8 pa = *(const short8*)(plds_w + r * 72 + ks * 32 + g * 8);
#pragma unroll
      for (int ct = 0; ct < 16; ct++) {
        short8 vf = *(const short8*)(kv + 16384 + (ct * 16 + r) * 64 +
                                     (((ks * 4 + g) ^ (r & 7)) * 8));
        o[ct] = MFMA(pa, vf, o[ct]);
      }
    }
    __builtin_amdgcn_s_setprio(0);
    if (ch < 15) __syncthreads();  // readers done before next st_chunk
  }
#pragma unroll
  for (int d = 1; d < 16; d <<= 1)
#pragma unroll
    for (int j = 0; j < 4; j++) lsum[j] += __shfl_xor(lsum[j], d);
  float inv[4];
#pragma unroll
  for (int j = 0; j < 4; j++) inv[j] = 1.0f / lsum[j];
  short* ao = attout + (size_t)b * 8192 * 256;
#pragma unroll
  for (int ct = 0; ct < 16; ct++)
#pragma unroll
    for (int j = 0; j < 4; j++) {
      float vv = fmaxf(o[ct][j] * inv[j], 0.f);  // relu fused here
      ao[(size_t)(q0 + 4 * g + j) * 256 + ct * 16 + r] = f2bf(vv);
    }
}

// ---------------- kernel 5: output projection GEMM (m97 structure) --------
// out[m][n] = (sum_k Wob[m][k] * attout[n][k] + bo[m]) * mask[n]
// 1-D grid (1024) + T1 XCD swizzle: the 4 mtile blocks sharing a (n0,b)
// B-panel (64 KB of attout) co-locate on one XCD (bijective: 128 = 4*32).
__global__ __launch_bounds__(256, 2) void gemm_out(
    const short* __restrict__ Wob, const float* __restrict__ bo,
    const short* __restrict__ attout, const float* __restrict__ mask,
    float* __restrict__ out) {
  __shared__ __align__(16) short lds[8192];  // A[128][32] | B[128][32]
  int t = threadIdx.x, w = t >> 6, l = t & 63;
  int r = l & 15, g = l >> 4;
  int wr = w >> 1, wc = w & 1;
  // --- XCD-locality swizzle decode (bijective over 1024) ---
  int id = blockIdx.x;
  int xcd = id & 7, j = id >> 3;        // j in 0..127
  int grp = j >> 2, member = j & 3;     // grp 0..31, member 0..3
  int g_total = xcd * 32 + grp;         // 0..255
  int n0 = (g_total >> 2) * 128, b = g_total & 3;
  int m00 = member * 128;
  const short* Ab = Wob + (size_t)m00 * 256;
  const short* Bb = attout + (size_t)b * 8192 * 256 + (size_t)n0 * 256;
  int c0 = w * 64 + l, c1 = 256 + w * 64 + l;
  int a0r = c0 >> 2, a0c = (c0 & 3) * 8, a1r = c1 >> 2, a1c = (c1 & 3) * 8;

  f32x4 acc[4][4];
#pragma unroll
  for (int i = 0; i < 4; i++)
#pragma unroll
    for (int jj = 0; jj < 4; jj++) acc[i][jj] = {0.f, 0.f, 0.f, 0.f};

  for (int kk = 0; kk < 8; kk++) {
    const short* ga = Ab + kk * 32;
    const short* gb = Bb + kk * 32;
    glds16(ga + (size_t)a0r * 256 + a0c, lds + (w * 64) * 8);
    glds16(ga + (size_t)a1r * 256 + a1c, lds + (256 + w * 64) * 8);
    glds16(gb + (size_t)a0r * 256 + a0c, lds + 4096 + (w * 64) * 8);
    glds16(gb + (size_t)a1r * 256 + a1c, lds + 4096 + (256 + w * 64) * 8);
    __syncthreads();
    short8 af[4], bfv[4];
#pragma unroll
    for (int mt = 0; mt < 4; mt++)
      af[mt] = *(const short8*)(lds + (wr * 64 + mt * 16 + r) * 32 + g * 8);
#pragma unroll
    for (int nt = 0; nt < 4; nt++)
      bfv[nt] = *(const short8*)(lds + 4096 + (wc * 64 + nt * 16 + r) * 32 + g * 8);
#pragma unroll
    for (int mt = 0; mt < 4; mt++)
#pragma unroll
      for (int nt = 0; nt < 4; nt++) acc[mt][nt] = MFMA(af[mt], bfv[nt], acc[mt][nt]);
    __syncthreads();
  }

  float* ob = out + (size_t)b * 512 * 8192;
#pragma unroll
  for (int nt = 0; nt < 4; nt++) {
    int n = n0 + wc * 64 + nt * 16 + r;
    float mv = mask[(size_t)b * 8192 + n];
#pragma unroll
    for (int mt = 0; mt < 4; mt++)
#pragma unroll
      for (int jj = 0; jj < 4; jj++) {
        int m = m00 + wr * 64 + mt * 16 + 4 * g + jj;
        ob[(size_t)m * 8192 + n] = (acc[mt][nt][jj] + bo[m]) * mv;
      }
  }
}

extern "C" void kernel_launch(void* const* d_in, const int* in_sizes, int n_in,
                              void* d_out, int out_size, void* d_ws, size_t ws_size,
                              hipStream_t stream) {
  const float* x1 = (const float*)d_in[0];
  const float* mask = (const float*)d_in[1];
  const float* Wq = (const float*)d_in[2];
  const float* bq = (const float*)d_in[3];
  const float* Wk = (const float*)d_in[4];
  const float* bk = (const float*)d_in[5];
  const float* Wv = (const float*)d_in[6];
  const float* bv = (const float*)d_in[7];
  const float* Wo = (const float*)d_in[8];
  const float* bo = (const float*)d_in[9];

  char* ws = (char*)d_ws;
  size_t off = 0;
  short* xT = (short*)(ws + off);  off += (size_t)4 * 8192 * 512 * 2;   // 32 MB
  short* q_t = (short*)(ws + off); off += (size_t)4 * 8192 * 256 * 2;   // 16 MB
  short* k_t = (short*)(ws + off); off += (size_t)4 * 8192 * 256 * 2;   // 16 MB
  short* v_tt = (short*)(ws + off); off += (size_t)4 * 8192 * 256 * 2;  // 16 MB
  short* aout = (short*)(ws + off); off += (size_t)4 * 8192 * 256 * 2;  // 16 MB
  short* Wb3 = (short*)(ws + off); off += 768 * 512 * 2;
  short* Wob = (short*)(ws + off); off += 512 * 256 * 2;
  float* b3 = (float*)(ws + off);  off += 768 * 4;
  // total ~97 MB of ws used

  convert_w<<<dim3(2051), dim3(256), 0, stream>>>(Wq, Wk, Wv, Wo, bq, bk, bv, Wb3, Wob, b3);
  transpose_x<<<dim3(128, 8, 4), dim3(256), 0, stream>>>(x1, xT);
  gemm_qkv<<<dim3(1536), dim3(256), 0, stream>>>(Wb3, b3, xT, q_t, k_t, v_tt);
  attn<<<dim3(512), dim3(256), 0, stream>>>(q_t, k_t, v_tt, mask, aout);
  gemm_out<<<dim3(1024), dim3(256), 0, stream>>>(Wob, bo, aout, mask, (float*)d_out);
}